// Round 13
// baseline (143.680 us; speedup 1.0000x reference)
//
#include <hip/hip_runtime.h>
#include <hip/hip_bf16.h>

typedef __hip_bfloat16 bf16;
typedef __bf16 bf16x8 __attribute__((ext_vector_type(8)));
typedef float f32x16 __attribute__((ext_vector_type(16)));

union Frag { uint4 q; bf16x8 v; unsigned short us[8]; };

#define PI_D 3.14159265358979323846

__device__ __forceinline__ unsigned short bfbits(float x){ bf16 h = __float2bfloat16(x); return *(unsigned short*)&h; }
__device__ __forceinline__ float frombits(unsigned short b){ union{float f; unsigned u;}v; v.u = ((unsigned)b)<<16; return v.f; }

#define GLD_LDS16(gp, lp) __builtin_amdgcn_global_load_lds( \
    (const __attribute__((address_space(1))) unsigned int*)(gp), \
    (__attribute__((address_space(3))) unsigned int*)(lp), 16, 0, 0)

// ---------------- init: MLP fragment tables + folded bias + r-table ----------------
__global__ void k_init(const float* __restrict__ W1, const float* __restrict__ b1,
                       const float* __restrict__ W2, const float* __restrict__ b2,
                       const float* __restrict__ coef,
                       bf16* __restrict__ W1f, bf16* __restrict__ W2A2f,
                       float* __restrict__ rtab, float* __restrict__ bias2p) {
    int idx = blockIdx.x * 256 + threadIdx.x;
    if (idx < 96) {
        float acc = b2[idx];
        for (int h = 0; h < 384; ++h) {
            float bb = b1[h], C0 = coef[h*3], C1 = coef[h*3+1], C2 = coef[h*3+2];
            float A0 = C0 + C1 * bb + C2 * bb * bb;
            acc += W2[idx * 384 + h] * A0;
        }
        bias2p[idx] = acc;
    }
    if (idx < 384) {
        float bb = b1[idx], C1 = coef[idx*3+1], C2 = coef[idx*3+2];
        rtab[idx] = (C1 + 2.f * C2 * bb) / C2;   // r = A1/A2
    }
    if (idx < 36864) {
        int j = idx & 7, lane = (idx >> 3) & 63, rest = idx >> 9;
        int g2 = lane >> 5;
        {   // W1f: layout ((ht*6+s)*64+lane)*8+j, rows permuted by pi
            int s = rest % 6, ht = rest / 6;
            int p = lane & 31;
            int b = p >> 2, m4 = b & 3; if (m4 == 1 || m4 == 2) b ^= 3;
            int h = ht * 32 + ((b << 2) | (p & 3));
            int k = s * 16 + g2 * 8 + j;
            W1f[idx] = __float2bfloat16(W1[h * 96 + k]);
        }
        {   // W2A2f: layout (((ht*3+ct)*2+s)*64+lane)*8+j, natural h
            int s = rest & 1, rest2 = rest >> 1;
            int ct = rest2 % 3, ht = rest2 / 3;
            int c = ct * 32 + (lane & 31);
            int h = ht * 32 + s * 16 + g2 * 8 + j;
            float C2 = coef[h*3+2];
            W2A2f[idx] = __float2bfloat16(W2[c * 384 + h] * C2);
        }
    }
}

// ---------------- init2: FIR filter A-fragment tables (split hi/lo) ----------------
__global__ void k_init2(bf16* __restrict__ upA, bf16* __restrict__ lpA) {
    int idx = blockIdx.x * 256 + threadIdx.x;   // 0..24575
    int e = (idx < 12288) ? idx : idx - 12288;
    int j = e & 7, lane = (e >> 3) & 63, mt = (e >> 9) & 1, step = e >> 10;
    int m = 32 * mt + (lane & 31);
    int p = (step & 3) * 16 + (lane >> 5) * 8 + j;
    int d2 = 2 * (m - p);
    int n = ((idx < 12288) ? (d2 + 1) : (d2 - 1)) & 127;   // odd -> c32 term vanishes
    double s = 1.0;
    for (int k = 1; k <= 31; ++k) s += 2.0 * cos((2.0 * PI_D / 128.0) * (double)k * (double)n);
    float F = (float)(s / ((idx < 12288) ? 64.0 : 128.0));
    bf16 fh = __float2bfloat16(F);
    bf16 val = (step < 8) ? fh : __float2bfloat16(F - __bfloat162float(fh));
    (idx < 12288 ? upA : lpA)[((step * 2 + mt) * 64 + lane) * 8 + j] = val;
}

// ---------------- FIR A-fragment preload ----------------
__device__ __forceinline__ void fir_load_a12(const uint4* __restrict__ atab,
                                             int lane, int mt, Frag af[12]) {
    #pragma unroll
    for (int s = 0; s < 12; ++s) af[s].q = atab[(s * 2 + mt) * 64 + lane];
}
__device__ __forceinline__ void fir_load_a8(const uint4* __restrict__ atab,
                                            int lane, int mt, Frag af[8]) {
    #pragma unroll
    for (int s = 0; s < 8; ++s) {
        int st = (s < 4) ? s : (s + 4);   // steps 0-3 (F_hi) and 8-11 (F_lo)
        af[s].q = atab[(st * 2 + mt) * 64 + lane];
    }
}

// ---------------- FIR GEMM core, f32 input (split K=192), B stride 256 ----------------
__device__ __forceinline__ f32x16 fir_gemm(const Frag af[12],
                                           const unsigned char* BtS,
                                           int lane, int nt) {
    const int n = 32 * nt + (lane & 31);
    const int rowbase = n * 256;
    const int swz = (n & 7) << 4;
    const int g16 = (lane >> 5) * 16;
    f32x16 C;
    #pragma unroll
    for (int e = 0; e < 16; ++e) C[e] = 0.f;
    #pragma unroll
    for (int s = 0; s < 12; ++s) {
        int k2 = (s & 3) * 32 + (((s >> 2) == 1) ? 128 : 0) + g16;
        Frag bf_;
        bf_.q = *(const uint4*)(BtS + rowbase + (k2 ^ swz));
        C = __builtin_amdgcn_mfma_f32_32x32x16_bf16(af[s].v, bf_.v, C, 0, 0, 0);
    }
    return C;
}

// ---------------- FIR GEMM core, bf16 input (hi-only K=128), B stride 128 ----------------
__device__ __forceinline__ f32x16 fir_gemm_h(const Frag af[8],
                                             const unsigned char* BtS,
                                             int lane, int nt) {
    const int n = 32 * nt + (lane & 31);
    const int rowbase = n * 128;
    const int swz = (n & 7) << 4;
    const int g16 = (lane >> 5) * 16;
    f32x16 C;
    #pragma unroll
    for (int e = 0; e < 16; ++e) C[e] = 0.f;
    #pragma unroll
    for (int s = 0; s < 8; ++s) {
        int k2 = (s & 3) * 32 + g16;
        Frag bf_;
        bf_.q = *(const uint4*)(BtS + rowbase + (k2 ^ swz));
        C = __builtin_amdgcn_mfma_f32_32x32x16_bf16(af[s].v, bf_.v, C, 0, 0, 0);
    }
    return C;
}

// ---------------- A1: vertical upsample 64->128 (f32 in, bf16 out), paired-k staging ----------------
__global__ __launch_bounds__(384, 2) void k_up_v(const float* __restrict__ x,
                                                 const uint4* __restrict__ atab,
                                                 bf16* __restrict__ t1) {
    __shared__ __align__(16) unsigned char BtS[24576];
    __shared__ __align__(16) float xe[64 * 96];
    __shared__ float As[96];
    const int tid = threadIdx.x;
    const int lane = tid & 63, w = tid >> 6;
    const int b = blockIdx.x >> 6, q = blockIdx.x & 63;
    Frag af[12];
    fir_load_a12(atab, lane, w / 3, af);
    for (int g = tid; g < 768; g += 384) {
        int pp = g / 24, c4 = (g - pp * 24) * 4;   // pair pp: p = 2pp, 2pp+1
        const float* xsrc = &x[((b * 64 + 2 * pp) * 64 + q) * 96 + c4];
        float4 v0 = *(const float4*)xsrc;
        float4 v1 = *(const float4*)(xsrc + 6144);
        *(float4*)&xe[(2 * pp) * 96 + c4] = v0;
        *(float4*)&xe[(2 * pp + 1) * 96 + c4] = v1;
        float f0a[4] = {v0.x, v0.y, v0.z, v0.w};
        float f1a[4] = {v1.x, v1.y, v1.z, v1.w};
        #pragma unroll
        for (int e = 0; e < 4; ++e) {
            int n = c4 + e;
            unsigned short h0 = bfbits(f0a[e]), h1 = bfbits(f1a[e]);
            unsigned short l0 = bfbits(f0a[e] - frombits(h0));
            unsigned short l1 = bfbits(f1a[e] - frombits(h1));
            int base = n * 256 + ((4 * pp) ^ ((n & 7) << 4));
            *(unsigned*)(BtS + base) = (unsigned)h0 | ((unsigned)h1 << 16);
            *(unsigned*)(BtS + base + 128) = (unsigned)l0 | ((unsigned)l1 << 16);
        }
    }
    __syncthreads();
    if (tid < 96) {
        float a = 0.f;
        for (int p = 0; p < 64; p += 2) a += xe[p * 96 + tid] - xe[(p + 1) * 96 + tid];
        As[tid] = a * 0.015625f;
    }
    __syncthreads();
    f32x16 C = fir_gemm(af, BtS, lane, w % 3);
    bf16* dst = t1 + (size_t)b * 786432 + (size_t)q * 96;   // + i*6144 + c
    const int c = 32 * (w % 3) + (lane & 31);
    #pragma unroll
    for (int r = 0; r < 16; ++r) {
        int m = 32 * (w / 3) + (r & 3) + 8 * (r >> 2) + 4 * (lane >> 5);
        dst[(size_t)(2 * m + 1) * 6144 + c] = __float2bfloat16(C[r]);
    }
    for (int g = tid; g < 1536; g += 384) {
        int u = g / 24, c4 = (g - u * 24) * 4;
        float sgn = (u & 1) ? -1.f : 1.f;
        float4 xv = *(const float4*)&xe[u * 96 + c4];
        float4 av = *(const float4*)&As[c4];
        uint2 pk;
        pk.x = (unsigned)bfbits(fmaf(sgn, av.x, xv.x)) | ((unsigned)bfbits(fmaf(sgn, av.y, xv.y)) << 16);
        pk.y = (unsigned)bfbits(fmaf(sgn, av.z, xv.z)) | ((unsigned)bfbits(fmaf(sgn, av.w, xv.w)) << 16);
        *(uint2*)&dst[(size_t)(2 * u) * 6144 + c4] = pk;
    }
}

// ---------------- A2: horizontal upsample 64->128 (bf16 in, hi-only), paired-k ----------------
__global__ __launch_bounds__(384, 2) void k_up_h(const bf16* __restrict__ t1,
                                                 const uint4* __restrict__ atab,
                                                 bf16* __restrict__ xu) {
    __shared__ __align__(16) unsigned char BtS[96 * 128];   // 12KB hi-only
    __shared__ __align__(16) bf16 xe[64 * 96];              // 12KB
    __shared__ float As[96];
    const int tid = threadIdx.x;
    const int lane = tid & 63, w = tid >> 6;
    const size_t row = blockIdx.x;
    const bf16* src = t1 + row * 6144;
    Frag af[8];
    fir_load_a8(atab, lane, w / 3, af);
    {   // 384 iters: exactly 1 per thread; pair p = 2pp, 2pp+1
        int pp = tid / 12, c8 = (tid - pp * 12) * 8;
        const bf16* s0 = src + (2 * pp) * 96 + c8;
        uint4 v0 = *(const uint4*)s0;
        uint4 v1 = *(const uint4*)(s0 + 96);
        *(uint4*)&xe[(2 * pp) * 96 + c8] = v0;
        *(uint4*)&xe[(2 * pp + 1) * 96 + c8] = v1;
        const unsigned short* u0 = (const unsigned short*)&v0;
        const unsigned short* u1 = (const unsigned short*)&v1;
        #pragma unroll
        for (int e = 0; e < 8; ++e) {
            int n = c8 + e;
            int base = n * 128 + ((4 * pp) ^ ((n & 7) << 4));
            *(unsigned*)(BtS + base) = (unsigned)u0[e] | ((unsigned)u1[e] << 16);
        }
    }
    __syncthreads();
    if (tid < 96) {
        float a = 0.f;
        for (int p = 0; p < 64; p += 2)
            a += __bfloat162float(xe[p * 96 + tid]) - __bfloat162float(xe[(p + 1) * 96 + tid]);
        As[tid] = a * 0.015625f;
    }
    __syncthreads();
    f32x16 C = fir_gemm_h(af, BtS, lane, w % 3);
    bf16* dst = xu + row * 12288;
    const int c = 32 * (w % 3) + (lane & 31);
    #pragma unroll
    for (int r = 0; r < 16; ++r) {
        int m = 32 * (w / 3) + (r & 3) + 8 * (r >> 2) + 4 * (lane >> 5);
        dst[(2 * m + 1) * 96 + c] = __float2bfloat16(C[r]);
    }
    for (int g = tid; g < 1536; g += 384) {
        int v = g / 24, c4 = (g - v * 24) * 4;
        float sgn = (v & 1) ? -1.f : 1.f;
        uint2 xv = *(const uint2*)&xe[v * 96 + c4];
        const unsigned short* us = (const unsigned short*)&xv;
        uint2 pk;
        pk.x = (unsigned)bfbits(fmaf(sgn, As[c4 + 0], frombits(us[0])))
             | ((unsigned)bfbits(fmaf(sgn, As[c4 + 1], frombits(us[1]))) << 16);
        pk.y = (unsigned)bfbits(fmaf(sgn, As[c4 + 2], frombits(us[2])))
             | ((unsigned)bfbits(fmaf(sgn, As[c4 + 3], frombits(us[3]))) << 16);
        *(uint2*)&dst[(2 * v) * 96 + c4] = pk;
    }
}

// ---------------- M: MFMA MLP, 1 m-tile/wave, 2 rows/block, W1f-only LDS ----------------
// (512,4): 16 waves/CU.  a2f prefetch split 3+3 to keep max-live regs under the
// 128-unified budget (R12's spill source).  No barriers in the ht loop.
__global__ __launch_bounds__(512, 4) void k_mlp(const bf16* __restrict__ xu,
                                                const uint4* __restrict__ W1f,
                                                const uint4* __restrict__ W2A2f,
                                                const float* __restrict__ rtabg,
                                                const float* __restrict__ bias2p,
                                                bf16* __restrict__ y) {
    extern __shared__ __align__(16) uint4 wAll[];   // 72*64 uint4 (73728B) + 1536B rtab
    float* rtabL = (float*)(wAll + 72 * 64);
    const int tid = threadIdx.x;
    const int lane = tid & 63;
    const int w = tid >> 6;          // 0..7
    const int rw = w >> 2;           // row within block 0..1
    const int mt = w & 3;            // m-tile 0..3
    const int lm = lane & 31;
    const int g = lane >> 5;
    const size_t row = (size_t)blockIdx.x * 2 + rw;

    // stage W1f (72 chunks) + rtab
    for (int c = w; c < 72; c += 8)
        GLD_LDS16(W1f + c * 64 + lane, &wAll[c * 64]);
    if (tid < 96) GLD_LDS16(rtabg + tid * 4, rtabL + tid * 4);

    // x fragments (overlap staging latency)
    Frag xr[6];
    const bf16* xb = xu + row * 12288 + (size_t)(mt * 32 + lm) * 96 + g * 8;
    #pragma unroll
    for (int s = 0; s < 6; ++s) xr[s].q = *(const uint4*)(xb + 16 * s);

    asm volatile("s_waitcnt vmcnt(0)" ::: "memory");
    __syncthreads();   // the ONLY barrier

    f32x16 ya[3];
    #pragma unroll
    for (int ct = 0; ct < 3; ++ct) {
        #pragma unroll
        for (int e = 0; e < 16; ++e) ya[ct][e] = 0.f;
    }

    for (int ht = 0; ht < 12; ++ht) {
        // prefetch first half of W2A2f fragments (used by GEMM2 u=0..2)
        Frag a2fA[3];
        #pragma unroll
        for (int u = 0; u < 3; ++u) a2fA[u].q = W2A2f[(ht * 6 + u) * 64 + lane];
        // GEMM1 from LDS W1f
        f32x16 d;
        #pragma unroll
        for (int e = 0; e < 16; ++e) d[e] = 0.f;
        #pragma unroll
        for (int s = 0; s < 6; ++s) {
            Frag a; a.q = wAll[(ht * 6 + s) * 64 + lane];
            d = __builtin_amdgcn_mfma_f32_32x32x16_bf16(a.v, xr[s].v, d, 0, 0, 0);
        }
        // prefetch second half (used by GEMM2 u=3..5, ~pack+3 MFMAs later)
        Frag a2fB[3];
        #pragma unroll
        for (int u = 0; u < 3; ++u) a2fB[u].q = W2A2f[(ht * 6 + 3 + u) * 64 + lane];
        // pack e = d*(d+r); r from LDS
        Frag be[2];
        #pragma unroll
        for (int s2 = 0; s2 < 2; ++s2) {
            #pragma unroll
            for (int j = 0; j < 8; ++j) {
                float rv = rtabL[ht * 32 + s2 * 16 + g * 8 + j];
                float v0 = d[s2 * 8 + j];
                be[s2].v[j] = (__bf16)(v0 * (v0 + rv));
            }
        }
        // GEMM2: 6 MFMAs
        ya[0] = __builtin_amdgcn_mfma_f32_32x32x16_bf16(a2fA[0].v, be[0].v, ya[0], 0, 0, 0);
        ya[0] = __builtin_amdgcn_mfma_f32_32x32x16_bf16(a2fA[1].v, be[1].v, ya[0], 0, 0, 0);
        ya[1] = __builtin_amdgcn_mfma_f32_32x32x16_bf16(a2fA[2].v, be[0].v, ya[1], 0, 0, 0);
        ya[1] = __builtin_amdgcn_mfma_f32_32x32x16_bf16(a2fB[0].v, be[1].v, ya[1], 0, 0, 0);
        ya[2] = __builtin_amdgcn_mfma_f32_32x32x16_bf16(a2fB[1].v, be[0].v, ya[2], 0, 0, 0);
        ya[2] = __builtin_amdgcn_mfma_f32_32x32x16_bf16(a2fB[2].v, be[1].v, ya[2], 0, 0, 0);
    }
    // epilogue: y bf16 [row][m][c]
    bf16* yb = y + row * 12288 + (size_t)(mt * 32 + lm) * 96;
    #pragma unroll
    for (int ct = 0; ct < 3; ++ct) {
        #pragma unroll
        for (int t = 0; t < 8; ++t) {
            int cbase = 32 * ct + 8 * (t >> 1) + 2 * (t & 1) + 4 * g;
            float bb0 = bias2p[cbase], bb1 = bias2p[cbase + 1];
            unsigned pk = (unsigned)bfbits(ya[ct][2*t] + bb0) | ((unsigned)bfbits(ya[ct][2*t+1] + bb1) << 16);
            *(unsigned*)(yb + cbase) = pk;
        }
    }
}

// ---------------- C1: vertical LPF + decimate 128->64, bf16 in/out, 2 cols/block, paired-k ----------------
__global__ __launch_bounds__(384, 2) void k_lpf_v(const bf16* __restrict__ y,
                                                  const uint4* __restrict__ atab,
                                                  bf16* __restrict__ t2) {
    __shared__ __align__(16) unsigned char BtS[192 * 128];   // 24 KB, hi only
    __shared__ __align__(16) bf16 xe[64 * 192];              // 24 KB even rows
    const int tid = threadIdx.x;
    const int lane = tid & 63, w = tid >> 6;
    const int b = blockIdx.x >> 6, j2 = blockIdx.x & 63;
    // even rows -> xe (2 iters/thread)
    for (int g = tid; g < 1536; g += 384) {
        int ie = g / 24, rem = g - ie * 24, col = rem / 12, c8 = (rem - col * 12) * 8;
        uint4 v = *(const uint4*)(y + ((size_t)((b * 128 + 2 * ie) * 128 + 2 * j2 + col)) * 96 + c8);
        *(uint4*)&xe[ie * 192 + col * 96 + c8] = v;
    }
    // odd rows paired (k=2q from i=4q+1, k=2q+1 from i=4q+3) -> BtS (2 iters/thread)
    for (int g = tid; g < 768; g += 384) {
        int q_ = g / 24, rem = g - q_ * 24, col = rem / 12, c8 = (rem - col * 12) * 8;
        const bf16* yb = y + ((size_t)((b * 128 + 4 * q_ + 1) * 128 + 2 * j2 + col)) * 96 + c8;
        uint4 v0 = *(const uint4*)yb;
        uint4 v1 = *(const uint4*)(yb + 2 * 12288);
        int np = col * 96 + c8;
        const unsigned short* u0 = (const unsigned short*)&v0;
        const unsigned short* u1 = (const unsigned short*)&v1;
        #pragma unroll
        for (int e = 0; e < 8; ++e) {
            int n = np + e;
            int base = n * 128 + ((4 * q_) ^ ((n & 7) << 4));
            *(unsigned*)(BtS + base) = (unsigned)u0[e] | ((unsigned)u1[e] << 16);
        }
    }
    __syncthreads();
    // wave w -> n-tile w (N'=192); both m-tiles, B-frags shared
    const int n = 32 * w + (lane & 31);
    const int rowbase = n * 128;
    const int swz = (n & 7) << 4;
    const int g16 = (lane >> 5) * 16;
    f32x16 C0, C1;
    #pragma unroll
    for (int e = 0; e < 16; ++e) { C0[e] = 0.f; C1[e] = 0.f; }
    #pragma unroll
    for (int s = 0; s < 4; ++s) {
        Frag bf_; bf_.q = *(const uint4*)(BtS + rowbase + ((s * 32 + g16) ^ swz));
        Frag a0h; a0h.q = atab[(s * 2 + 0) * 64 + lane];
        Frag a1h; a1h.q = atab[(s * 2 + 1) * 64 + lane];
        Frag a0l; a0l.q = atab[((8 + s) * 2 + 0) * 64 + lane];
        Frag a1l; a1l.q = atab[((8 + s) * 2 + 1) * 64 + lane];
        C0 = __builtin_amdgcn_mfma_f32_32x32x16_bf16(a0h.v, bf_.v, C0, 0, 0, 0);
        C1 = __builtin_amdgcn_mfma_f32_32x32x16_bf16(a1h.v, bf_.v, C1, 0, 0, 0);
        C0 = __builtin_amdgcn_mfma_f32_32x32x16_bf16(a0l.v, bf_.v, C0, 0, 0, 0);
        C1 = __builtin_amdgcn_mfma_f32_32x32x16_bf16(a1l.v, bf_.v, C1, 0, 0, 0);
    }
    const int col = n / 96;
    const int c = n - col * 96;
    const int j = 2 * j2 + col;
    #pragma unroll
    for (int r = 0; r < 16; ++r) {
        int mrow = (r & 3) + 8 * (r >> 2) + 4 * (lane >> 5);
        t2[(size_t)((b * 64 + mrow) * 128 + j) * 96 + c] =
            __float2bfloat16(C0[r] + 0.5f * __bfloat162float(xe[mrow * 192 + n]));
        t2[(size_t)((b * 64 + 32 + mrow) * 128 + j) * 96 + c] =
            __float2bfloat16(C1[r] + 0.5f * __bfloat162float(xe[(32 + mrow) * 192 + n]));
    }
}

// ---------------- C2: horizontal LPF + decimate 128->64 (bf16 in, hi-only), paired-k, f32 out ----------------
__global__ __launch_bounds__(384, 2) void k_lpf_h(const bf16* __restrict__ t2,
                                                  const uint4* __restrict__ atab,
                                                  float* __restrict__ out) {
    __shared__ __align__(16) unsigned char BtS[96 * 128];   // 12KB hi-only
    __shared__ __align__(16) bf16 xe[64 * 96];              // 12KB
    const int tid = threadIdx.x;
    const int lane = tid & 63, w = tid >> 6;
    const size_t row = blockIdx.x;   // b*64+u
    const bf16* src = t2 + row * 12288;
    Frag af[8];
    fir_load_a8(atab, lane, w / 3, af);
    // even cols -> xe (2 iters/thread)
    for (int g = tid; g < 768; g += 384) {
        int ce = g / 12, c8 = (g - ce * 12) * 8;
        uint4 v = *(const uint4*)(src + (2 * ce) * 96 + c8);
        *(uint4*)&xe[ce * 96 + c8] = v;
    }
    // odd cols paired (k=2q from col=4q+1, k=2q+1 from col=4q+3): 1 iter/thread
    {
        int q_ = tid / 12, c8 = (tid - q_ * 12) * 8;
        const bf16* s0 = src + (4 * q_ + 1) * 96 + c8;
        uint4 v0 = *(const uint4*)s0;
        uint4 v1 = *(const uint4*)(s0 + 2 * 96);
        const unsigned short* u0 = (const unsigned short*)&v0;
        const unsigned short* u1 = (const unsigned short*)&v1;
        #pragma unroll
        for (int e = 0; e < 8; ++e) {
            int n = c8 + e;
            int base = n * 128 + ((4 * q_) ^ ((n & 7) << 4));
            *(unsigned*)(BtS + base) = (unsigned)u0[e] | ((unsigned)u1[e] << 16);
        }
    }
    __syncthreads();
    f32x16 C = fir_gemm_h(af, BtS, lane, w % 3);
    const int c = 32 * (w % 3) + (lane & 31);
    #pragma unroll
    for (int r = 0; r < 16; ++r) {
        int m = 32 * (w / 3) + (r & 3) + 8 * (r >> 2) + 4 * (lane >> 5);
        out[row * 6144 + (size_t)m * 96 + c] = C[r] + 0.5f * __bfloat162float(xe[m * 96 + c]);
    }
}

extern "C" void kernel_launch(void* const* d_in, const int* in_sizes, int n_in,
                              void* d_out, int out_size, void* d_ws, size_t ws_size,
                              hipStream_t stream) {
    const float* x    = (const float*)d_in[0];
    const float* W1   = (const float*)d_in[1];
    const float* b1   = (const float*)d_in[2];
    const float* W2   = (const float*)d_in[3];
    const float* b2   = (const float*)d_in[4];
    const float* coef = (const float*)d_in[5];
    float* out = (float*)d_out;

    char* w = (char*)d_ws;
    float* bias2p = (float*)(w);                 // 96 f32 (pad 512)
    bf16*  W1f    = (bf16*)(w + 512);            // 36864 bf16 -> 74240
    bf16*  W2A2f  = (bf16*)(w + 74240);          // -> 147968
    float* rtab   = (float*)(w + 147968);        // 384 f32 -> 149504
    bf16*  atabU  = (bf16*)(w + 149504);         // 12288 bf16 -> 174080
    bf16*  atabL  = (bf16*)(w + 174080);         // -> 198656
    // data region: t1 (25.2MB bf16) aliases yv (50.3MB bf16); xu (50.3MB bf16)
    // aliases t2 (25.2MB bf16).
    bf16* t1 = (bf16*)(w + 270848);
    bf16* yv = (bf16*)(w + 270848);
    bf16* xu = (bf16*)(w + 100934144);
    bf16* t2 = (bf16*)(w + 100934144);

    k_init <<<144, 256, 0, stream>>>(W1, b1, W2, b2, coef, W1f, W2A2f, rtab, bias2p);
    k_init2<<<96, 256, 0, stream>>>(atabU, atabL);
    k_up_v <<<1024, 384, 0, stream>>>(x, (const uint4*)atabU, t1);
    k_up_h <<<2048, 384, 0, stream>>>(t1, (const uint4*)atabU, xu);
    k_mlp  <<<1024, 512, 75264, stream>>>(xu, (const uint4*)W1f, (const uint4*)W2A2f,
                                          rtab, bias2p, yv);
    k_lpf_v<<<1024, 384, 0, stream>>>(yv, (const uint4*)atabL, t2);
    k_lpf_h<<<1024, 384, 0, stream>>>(t2, (const uint4*)atabL, out);
}

// Round 14
// 140.928 us; speedup vs baseline: 1.0195x; 1.0195x over previous
//
#include <hip/hip_runtime.h>
#include <hip/hip_bf16.h>

typedef __hip_bfloat16 bf16;
typedef __bf16 bf16x8 __attribute__((ext_vector_type(8)));
typedef float f32x16 __attribute__((ext_vector_type(16)));

union Frag { uint4 q; bf16x8 v; unsigned short us[8]; };

#define PI_D 3.14159265358979323846

__device__ __forceinline__ unsigned short bfbits(float x){ bf16 h = __float2bfloat16(x); return *(unsigned short*)&h; }
__device__ __forceinline__ float frombits(unsigned short b){ union{float f; unsigned u;}v; v.u = ((unsigned)b)<<16; return v.f; }

#define GLD_LDS16(gp, lp) __builtin_amdgcn_global_load_lds( \
    (const __attribute__((address_space(1))) unsigned int*)(gp), \
    (__attribute__((address_space(3))) unsigned int*)(lp), 16, 0, 0)

// ---------------- init: MLP fragment tables + folded bias + r-table ----------------
__global__ void k_init(const float* __restrict__ W1, const float* __restrict__ b1,
                       const float* __restrict__ W2, const float* __restrict__ b2,
                       const float* __restrict__ coef,
                       bf16* __restrict__ W1f, bf16* __restrict__ W2A2f,
                       float* __restrict__ rtab, float* __restrict__ bias2p) {
    int idx = blockIdx.x * 256 + threadIdx.x;
    if (idx < 96) {
        float acc = b2[idx];
        for (int h = 0; h < 384; ++h) {
            float bb = b1[h], C0 = coef[h*3], C1 = coef[h*3+1], C2 = coef[h*3+2];
            float A0 = C0 + C1 * bb + C2 * bb * bb;
            acc += W2[idx * 384 + h] * A0;
        }
        bias2p[idx] = acc;
    }
    if (idx < 384) {
        float bb = b1[idx], C1 = coef[idx*3+1], C2 = coef[idx*3+2];
        rtab[idx] = (C1 + 2.f * C2 * bb) / C2;   // r = A1/A2
    }
    if (idx < 36864) {
        int j = idx & 7, lane = (idx >> 3) & 63, rest = idx >> 9;
        int g2 = lane >> 5;
        {   // W1f: layout ((ht*6+s)*64+lane)*8+j, rows permuted by pi
            int s = rest % 6, ht = rest / 6;
            int p = lane & 31;
            int b = p >> 2, m4 = b & 3; if (m4 == 1 || m4 == 2) b ^= 3;
            int h = ht * 32 + ((b << 2) | (p & 3));
            int k = s * 16 + g2 * 8 + j;
            W1f[idx] = __float2bfloat16(W1[h * 96 + k]);
        }
        {   // W2A2f: layout (((ht*3+ct)*2+s)*64+lane)*8+j, natural h
            int s = rest & 1, rest2 = rest >> 1;
            int ct = rest2 % 3, ht = rest2 / 3;
            int c = ct * 32 + (lane & 31);
            int h = ht * 32 + s * 16 + g2 * 8 + j;
            float C2 = coef[h*3+2];
            W2A2f[idx] = __float2bfloat16(W2[c * 384 + h] * C2);
        }
    }
}

// ---------------- init2: FIR filter A-fragment tables (split hi/lo) ----------------
__global__ void k_init2(bf16* __restrict__ upA, bf16* __restrict__ lpA) {
    int idx = blockIdx.x * 256 + threadIdx.x;   // 0..24575
    int e = (idx < 12288) ? idx : idx - 12288;
    int j = e & 7, lane = (e >> 3) & 63, mt = (e >> 9) & 1, step = e >> 10;
    int m = 32 * mt + (lane & 31);
    int p = (step & 3) * 16 + (lane >> 5) * 8 + j;
    int d2 = 2 * (m - p);
    int n = ((idx < 12288) ? (d2 + 1) : (d2 - 1)) & 127;   // odd -> c32 term vanishes
    double s = 1.0;
    for (int k = 1; k <= 31; ++k) s += 2.0 * cos((2.0 * PI_D / 128.0) * (double)k * (double)n);
    float F = (float)(s / ((idx < 12288) ? 64.0 : 128.0));
    bf16 fh = __float2bfloat16(F);
    bf16 val = (step < 8) ? fh : __float2bfloat16(F - __bfloat162float(fh));
    (idx < 12288 ? upA : lpA)[((step * 2 + mt) * 64 + lane) * 8 + j] = val;
}

// ---------------- FIR A-fragment preload ----------------
__device__ __forceinline__ void fir_load_a12(const uint4* __restrict__ atab,
                                             int lane, int mt, Frag af[12]) {
    #pragma unroll
    for (int s = 0; s < 12; ++s) af[s].q = atab[(s * 2 + mt) * 64 + lane];
}
__device__ __forceinline__ void fir_load_a8(const uint4* __restrict__ atab,
                                            int lane, int mt, Frag af[8]) {
    #pragma unroll
    for (int s = 0; s < 8; ++s) {
        int st = (s < 4) ? s : (s + 4);   // steps 0-3 (F_hi) and 8-11 (F_lo)
        af[s].q = atab[(st * 2 + mt) * 64 + lane];
    }
}

// ---------------- FIR GEMM core, f32 input (split K=192), B stride 256 ----------------
__device__ __forceinline__ f32x16 fir_gemm(const Frag af[12],
                                           const unsigned char* BtS,
                                           int lane, int nt) {
    const int n = 32 * nt + (lane & 31);
    const int rowbase = n * 256;
    const int swz = (n & 7) << 4;
    const int g16 = (lane >> 5) * 16;
    f32x16 C;
    #pragma unroll
    for (int e = 0; e < 16; ++e) C[e] = 0.f;
    #pragma unroll
    for (int s = 0; s < 12; ++s) {
        int k2 = (s & 3) * 32 + (((s >> 2) == 1) ? 128 : 0) + g16;
        Frag bf_;
        bf_.q = *(const uint4*)(BtS + rowbase + (k2 ^ swz));
        C = __builtin_amdgcn_mfma_f32_32x32x16_bf16(af[s].v, bf_.v, C, 0, 0, 0);
    }
    return C;
}

// ---------------- FIR GEMM core, bf16 input (hi-only K=128), B stride 128 ----------------
__device__ __forceinline__ f32x16 fir_gemm_h(const Frag af[8],
                                             const unsigned char* BtS,
                                             int lane, int nt) {
    const int n = 32 * nt + (lane & 31);
    const int rowbase = n * 128;
    const int swz = (n & 7) << 4;
    const int g16 = (lane >> 5) * 16;
    f32x16 C;
    #pragma unroll
    for (int e = 0; e < 16; ++e) C[e] = 0.f;
    #pragma unroll
    for (int s = 0; s < 8; ++s) {
        int k2 = (s & 3) * 32 + g16;
        Frag bf_;
        bf_.q = *(const uint4*)(BtS + rowbase + (k2 ^ swz));
        C = __builtin_amdgcn_mfma_f32_32x32x16_bf16(af[s].v, bf_.v, C, 0, 0, 0);
    }
    return C;
}

// ---------------- A1: vertical upsample 64->128 (f32 in, bf16 out), paired-k staging ----------------
__global__ __launch_bounds__(384, 2) void k_up_v(const float* __restrict__ x,
                                                 const uint4* __restrict__ atab,
                                                 bf16* __restrict__ t1) {
    __shared__ __align__(16) unsigned char BtS[24576];
    __shared__ __align__(16) float xe[64 * 96];
    __shared__ float As[96];
    const int tid = threadIdx.x;
    const int lane = tid & 63, w = tid >> 6;
    const int b = blockIdx.x >> 6, q = blockIdx.x & 63;
    Frag af[12];
    fir_load_a12(atab, lane, w / 3, af);
    for (int g = tid; g < 768; g += 384) {
        int pp = g / 24, c4 = (g - pp * 24) * 4;   // pair pp: p = 2pp, 2pp+1
        const float* xsrc = &x[((b * 64 + 2 * pp) * 64 + q) * 96 + c4];
        float4 v0 = *(const float4*)xsrc;
        float4 v1 = *(const float4*)(xsrc + 6144);
        *(float4*)&xe[(2 * pp) * 96 + c4] = v0;
        *(float4*)&xe[(2 * pp + 1) * 96 + c4] = v1;
        float f0a[4] = {v0.x, v0.y, v0.z, v0.w};
        float f1a[4] = {v1.x, v1.y, v1.z, v1.w};
        #pragma unroll
        for (int e = 0; e < 4; ++e) {
            int n = c4 + e;
            unsigned short h0 = bfbits(f0a[e]), h1 = bfbits(f1a[e]);
            unsigned short l0 = bfbits(f0a[e] - frombits(h0));
            unsigned short l1 = bfbits(f1a[e] - frombits(h1));
            int base = n * 256 + ((4 * pp) ^ ((n & 7) << 4));
            *(unsigned*)(BtS + base) = (unsigned)h0 | ((unsigned)h1 << 16);
            *(unsigned*)(BtS + base + 128) = (unsigned)l0 | ((unsigned)l1 << 16);
        }
    }
    __syncthreads();
    if (tid < 96) {
        float a = 0.f;
        for (int p = 0; p < 64; p += 2) a += xe[p * 96 + tid] - xe[(p + 1) * 96 + tid];
        As[tid] = a * 0.015625f;
    }
    __syncthreads();
    f32x16 C = fir_gemm(af, BtS, lane, w % 3);
    bf16* dst = t1 + (size_t)b * 786432 + (size_t)q * 96;   // + i*6144 + c
    const int c = 32 * (w % 3) + (lane & 31);
    #pragma unroll
    for (int r = 0; r < 16; ++r) {
        int m = 32 * (w / 3) + (r & 3) + 8 * (r >> 2) + 4 * (lane >> 5);
        dst[(size_t)(2 * m + 1) * 6144 + c] = __float2bfloat16(C[r]);
    }
    for (int g = tid; g < 1536; g += 384) {
        int u = g / 24, c4 = (g - u * 24) * 4;
        float sgn = (u & 1) ? -1.f : 1.f;
        float4 xv = *(const float4*)&xe[u * 96 + c4];
        float4 av = *(const float4*)&As[c4];
        uint2 pk;
        pk.x = (unsigned)bfbits(fmaf(sgn, av.x, xv.x)) | ((unsigned)bfbits(fmaf(sgn, av.y, xv.y)) << 16);
        pk.y = (unsigned)bfbits(fmaf(sgn, av.z, xv.z)) | ((unsigned)bfbits(fmaf(sgn, av.w, xv.w)) << 16);
        *(uint2*)&dst[(size_t)(2 * u) * 6144 + c4] = pk;
    }
}

// ---------------- A2: horizontal upsample 64->128 (bf16 in, hi-only), paired-k ----------------
__global__ __launch_bounds__(384, 2) void k_up_h(const bf16* __restrict__ t1,
                                                 const uint4* __restrict__ atab,
                                                 bf16* __restrict__ xu) {
    __shared__ __align__(16) unsigned char BtS[96 * 128];   // 12KB hi-only
    __shared__ __align__(16) bf16 xe[64 * 96];              // 12KB
    __shared__ float As[96];
    const int tid = threadIdx.x;
    const int lane = tid & 63, w = tid >> 6;
    const size_t row = blockIdx.x;
    const bf16* src = t1 + row * 6144;
    Frag af[8];
    fir_load_a8(atab, lane, w / 3, af);
    {   // 384 iters: exactly 1 per thread; pair p = 2pp, 2pp+1
        int pp = tid / 12, c8 = (tid - pp * 12) * 8;
        const bf16* s0 = src + (2 * pp) * 96 + c8;
        uint4 v0 = *(const uint4*)s0;
        uint4 v1 = *(const uint4*)(s0 + 96);
        *(uint4*)&xe[(2 * pp) * 96 + c8] = v0;
        *(uint4*)&xe[(2 * pp + 1) * 96 + c8] = v1;
        const unsigned short* u0 = (const unsigned short*)&v0;
        const unsigned short* u1 = (const unsigned short*)&v1;
        #pragma unroll
        for (int e = 0; e < 8; ++e) {
            int n = c8 + e;
            int base = n * 128 + ((4 * pp) ^ ((n & 7) << 4));
            *(unsigned*)(BtS + base) = (unsigned)u0[e] | ((unsigned)u1[e] << 16);
        }
    }
    __syncthreads();
    if (tid < 96) {
        float a = 0.f;
        for (int p = 0; p < 64; p += 2)
            a += __bfloat162float(xe[p * 96 + tid]) - __bfloat162float(xe[(p + 1) * 96 + tid]);
        As[tid] = a * 0.015625f;
    }
    __syncthreads();
    f32x16 C = fir_gemm_h(af, BtS, lane, w % 3);
    bf16* dst = xu + row * 12288;
    const int c = 32 * (w % 3) + (lane & 31);
    #pragma unroll
    for (int r = 0; r < 16; ++r) {
        int m = 32 * (w / 3) + (r & 3) + 8 * (r >> 2) + 4 * (lane >> 5);
        dst[(2 * m + 1) * 96 + c] = __float2bfloat16(C[r]);
    }
    for (int g = tid; g < 1536; g += 384) {
        int v = g / 24, c4 = (g - v * 24) * 4;
        float sgn = (v & 1) ? -1.f : 1.f;
        uint2 xv = *(const uint2*)&xe[v * 96 + c4];
        const unsigned short* us = (const unsigned short*)&xv;
        uint2 pk;
        pk.x = (unsigned)bfbits(fmaf(sgn, As[c4 + 0], frombits(us[0])))
             | ((unsigned)bfbits(fmaf(sgn, As[c4 + 1], frombits(us[1]))) << 16);
        pk.y = (unsigned)bfbits(fmaf(sgn, As[c4 + 2], frombits(us[2])))
             | ((unsigned)bfbits(fmaf(sgn, As[c4 + 3], frombits(us[3]))) << 16);
        *(uint2*)&dst[(2 * v) * 96 + c4] = pk;
    }
}

// ---------------- M: MFMA MLP, 16 waves/block (4 rows), ALL weights LDS-resident ----------------
// One block per CU (148992B LDS): W1f + W2A2f + rtab all in LDS -> no global
// streaming in the ht loop -> arch regs fit the 128-unified budget at 4 waves/SIMD
// with ZERO spills.  No barriers in the ht loop.
__global__ __launch_bounds__(1024, 4) void k_mlp(const bf16* __restrict__ xu,
                                                 const uint4* __restrict__ W1f,
                                                 const uint4* __restrict__ W2A2f,
                                                 const float* __restrict__ rtabg,
                                                 const float* __restrict__ bias2p,
                                                 bf16* __restrict__ y) {
    extern __shared__ __align__(16) uint4 wAll[];   // 144*64 uint4 (147456B) + 1536B rtab
    float* rtabL = (float*)(wAll + 144 * 64);
    const int tid = threadIdx.x;
    const int lane = tid & 63;
    const int w = tid >> 6;          // 0..15
    const int rw = w >> 2;           // row within block 0..3
    const int mt = w & 3;            // m-tile 0..3
    const int lm = lane & 31;
    const int g = lane >> 5;
    const size_t row = (size_t)blockIdx.x * 4 + rw;

    // stage W1f (chunks 0..71) + W2A2f (chunks 72..143) + rtab
    for (int c = w; c < 144; c += 16) {
        const uint4* gp = (c < 72) ? (W1f + (size_t)c * 64)
                                   : (W2A2f + (size_t)(c - 72) * 64);
        GLD_LDS16(gp + lane, &wAll[c * 64]);
    }
    if (tid < 96) GLD_LDS16(rtabg + tid * 4, rtabL + tid * 4);

    // x fragments (overlap staging latency)
    Frag xr[6];
    const bf16* xb = xu + row * 12288 + (size_t)(mt * 32 + lm) * 96 + g * 8;
    #pragma unroll
    for (int s = 0; s < 6; ++s) xr[s].q = *(const uint4*)(xb + 16 * s);

    asm volatile("s_waitcnt vmcnt(0)" ::: "memory");
    __syncthreads();   // the ONLY barrier

    f32x16 ya[3];
    #pragma unroll
    for (int ct = 0; ct < 3; ++ct) {
        #pragma unroll
        for (int e = 0; e < 16; ++e) ya[ct][e] = 0.f;
    }

    for (int ht = 0; ht < 12; ++ht) {
        // GEMM1 from LDS W1f
        f32x16 d;
        #pragma unroll
        for (int e = 0; e < 16; ++e) d[e] = 0.f;
        #pragma unroll
        for (int s = 0; s < 6; ++s) {
            Frag a; a.q = wAll[(ht * 6 + s) * 64 + lane];
            d = __builtin_amdgcn_mfma_f32_32x32x16_bf16(a.v, xr[s].v, d, 0, 0, 0);
        }
        // pack e = d*(d+r); r from LDS
        Frag be[2];
        #pragma unroll
        for (int s2 = 0; s2 < 2; ++s2) {
            #pragma unroll
            for (int j = 0; j < 8; ++j) {
                float rv = rtabL[ht * 32 + s2 * 16 + g * 8 + j];
                float v0 = d[s2 * 8 + j];
                be[s2].v[j] = (__bf16)(v0 * (v0 + rv));
            }
        }
        // GEMM2: 6 MFMAs from LDS W2A2f
        #pragma unroll
        for (int u = 0; u < 6; ++u) {
            Frag a2; a2.q = wAll[(72 + ht * 6 + u) * 64 + lane];
            ya[u >> 1] = __builtin_amdgcn_mfma_f32_32x32x16_bf16(
                a2.v, (u & 1 ? be[1] : be[0]).v, ya[u >> 1], 0, 0, 0);
        }
    }
    // epilogue: y bf16 [row][m][c]
    bf16* yb = y + row * 12288 + (size_t)(mt * 32 + lm) * 96;
    #pragma unroll
    for (int ct = 0; ct < 3; ++ct) {
        #pragma unroll
        for (int t = 0; t < 8; ++t) {
            int cbase = 32 * ct + 8 * (t >> 1) + 2 * (t & 1) + 4 * g;
            float bb0 = bias2p[cbase], bb1 = bias2p[cbase + 1];
            unsigned pk = (unsigned)bfbits(ya[ct][2*t] + bb0) | ((unsigned)bfbits(ya[ct][2*t+1] + bb1) << 16);
            *(unsigned*)(yb + cbase) = pk;
        }
    }
}

// ---------------- C1: vertical LPF + decimate 128->64, bf16 in/out, 2 cols/block, paired-k ----------------
__global__ __launch_bounds__(384, 2) void k_lpf_v(const bf16* __restrict__ y,
                                                  const uint4* __restrict__ atab,
                                                  bf16* __restrict__ t2) {
    __shared__ __align__(16) unsigned char BtS[192 * 128];   // 24 KB, hi only
    __shared__ __align__(16) bf16 xe[64 * 192];              // 24 KB even rows
    const int tid = threadIdx.x;
    const int lane = tid & 63, w = tid >> 6;
    const int b = blockIdx.x >> 6, j2 = blockIdx.x & 63;
    // even rows -> xe (2 iters/thread)
    for (int g = tid; g < 1536; g += 384) {
        int ie = g / 24, rem = g - ie * 24, col = rem / 12, c8 = (rem - col * 12) * 8;
        uint4 v = *(const uint4*)(y + ((size_t)((b * 128 + 2 * ie) * 128 + 2 * j2 + col)) * 96 + c8);
        *(uint4*)&xe[ie * 192 + col * 96 + c8] = v;
    }
    // odd rows paired (k=2q from i=4q+1, k=2q+1 from i=4q+3) -> BtS (2 iters/thread)
    for (int g = tid; g < 768; g += 384) {
        int q_ = g / 24, rem = g - q_ * 24, col = rem / 12, c8 = (rem - col * 12) * 8;
        const bf16* yb = y + ((size_t)((b * 128 + 4 * q_ + 1) * 128 + 2 * j2 + col)) * 96 + c8;
        uint4 v0 = *(const uint4*)yb;
        uint4 v1 = *(const uint4*)(yb + 2 * 12288);
        int np = col * 96 + c8;
        const unsigned short* u0 = (const unsigned short*)&v0;
        const unsigned short* u1 = (const unsigned short*)&v1;
        #pragma unroll
        for (int e = 0; e < 8; ++e) {
            int n = np + e;
            int base = n * 128 + ((4 * q_) ^ ((n & 7) << 4));
            *(unsigned*)(BtS + base) = (unsigned)u0[e] | ((unsigned)u1[e] << 16);
        }
    }
    __syncthreads();
    // wave w -> n-tile w (N'=192); both m-tiles, B-frags shared
    const int n = 32 * w + (lane & 31);
    const int rowbase = n * 128;
    const int swz = (n & 7) << 4;
    const int g16 = (lane >> 5) * 16;
    f32x16 C0, C1;
    #pragma unroll
    for (int e = 0; e < 16; ++e) { C0[e] = 0.f; C1[e] = 0.f; }
    #pragma unroll
    for (int s = 0; s < 4; ++s) {
        Frag bf_; bf_.q = *(const uint4*)(BtS + rowbase + ((s * 32 + g16) ^ swz));
        Frag a0h; a0h.q = atab[(s * 2 + 0) * 64 + lane];
        Frag a1h; a1h.q = atab[(s * 2 + 1) * 64 + lane];
        Frag a0l; a0l.q = atab[((8 + s) * 2 + 0) * 64 + lane];
        Frag a1l; a1l.q = atab[((8 + s) * 2 + 1) * 64 + lane];
        C0 = __builtin_amdgcn_mfma_f32_32x32x16_bf16(a0h.v, bf_.v, C0, 0, 0, 0);
        C1 = __builtin_amdgcn_mfma_f32_32x32x16_bf16(a1h.v, bf_.v, C1, 0, 0, 0);
        C0 = __builtin_amdgcn_mfma_f32_32x32x16_bf16(a0l.v, bf_.v, C0, 0, 0, 0);
        C1 = __builtin_amdgcn_mfma_f32_32x32x16_bf16(a1l.v, bf_.v, C1, 0, 0, 0);
    }
    const int col = n / 96;
    const int c = n - col * 96;
    const int j = 2 * j2 + col;
    #pragma unroll
    for (int r = 0; r < 16; ++r) {
        int mrow = (r & 3) + 8 * (r >> 2) + 4 * (lane >> 5);
        t2[(size_t)((b * 64 + mrow) * 128 + j) * 96 + c] =
            __float2bfloat16(C0[r] + 0.5f * __bfloat162float(xe[mrow * 192 + n]));
        t2[(size_t)((b * 64 + 32 + mrow) * 128 + j) * 96 + c] =
            __float2bfloat16(C1[r] + 0.5f * __bfloat162float(xe[(32 + mrow) * 192 + n]));
    }
}

// ---------------- C2: horizontal LPF + decimate 128->64 (bf16 in, hi-only), paired-k, f32 out ----------------
__global__ __launch_bounds__(384, 2) void k_lpf_h(const bf16* __restrict__ t2,
                                                  const uint4* __restrict__ atab,
                                                  float* __restrict__ out) {
    __shared__ __align__(16) unsigned char BtS[96 * 128];   // 12KB hi-only
    __shared__ __align__(16) bf16 xe[64 * 96];              // 12KB
    const int tid = threadIdx.x;
    const int lane = tid & 63, w = tid >> 6;
    const size_t row = blockIdx.x;   // b*64+u
    const bf16* src = t2 + row * 12288;
    Frag af[8];
    fir_load_a8(atab, lane, w / 3, af);
    // even cols -> xe (2 iters/thread)
    for (int g = tid; g < 768; g += 384) {
        int ce = g / 12, c8 = (g - ce * 12) * 8;
        uint4 v = *(const uint4*)(src + (2 * ce) * 96 + c8);
        *(uint4*)&xe[ce * 96 + c8] = v;
    }
    // odd cols paired (k=2q from col=4q+1, k=2q+1 from col=4q+3): 1 iter/thread
    {
        int q_ = tid / 12, c8 = (tid - q_ * 12) * 8;
        const bf16* s0 = src + (4 * q_ + 1) * 96 + c8;
        uint4 v0 = *(const uint4*)s0;
        uint4 v1 = *(const uint4*)(s0 + 2 * 96);
        const unsigned short* u0 = (const unsigned short*)&v0;
        const unsigned short* u1 = (const unsigned short*)&v1;
        #pragma unroll
        for (int e = 0; e < 8; ++e) {
            int n = c8 + e;
            int base = n * 128 + ((4 * q_) ^ ((n & 7) << 4));
            *(unsigned*)(BtS + base) = (unsigned)u0[e] | ((unsigned)u1[e] << 16);
        }
    }
    __syncthreads();
    f32x16 C = fir_gemm_h(af, BtS, lane, w % 3);
    const int c = 32 * (w % 3) + (lane & 31);
    #pragma unroll
    for (int r = 0; r < 16; ++r) {
        int m = 32 * (w / 3) + (r & 3) + 8 * (r >> 2) + 4 * (lane >> 5);
        out[row * 6144 + (size_t)m * 96 + c] = C[r] + 0.5f * __bfloat162float(xe[m * 96 + c]);
    }
}

extern "C" void kernel_launch(void* const* d_in, const int* in_sizes, int n_in,
                              void* d_out, int out_size, void* d_ws, size_t ws_size,
                              hipStream_t stream) {
    const float* x    = (const float*)d_in[0];
    const float* W1   = (const float*)d_in[1];
    const float* b1   = (const float*)d_in[2];
    const float* W2   = (const float*)d_in[3];
    const float* b2   = (const float*)d_in[4];
    const float* coef = (const float*)d_in[5];
    float* out = (float*)d_out;

    char* w = (char*)d_ws;
    float* bias2p = (float*)(w);                 // 96 f32 (pad 512)
    bf16*  W1f    = (bf16*)(w + 512);            // 36864 bf16 -> 74240
    bf16*  W2A2f  = (bf16*)(w + 74240);          // -> 147968
    float* rtab   = (float*)(w + 147968);        // 384 f32 -> 149504
    bf16*  atabU  = (bf16*)(w + 149504);         // 12288 bf16 -> 174080
    bf16*  atabL  = (bf16*)(w + 174080);         // -> 198656
    // data region: t1 (25.2MB bf16) aliases yv (50.3MB bf16); xu (50.3MB bf16)
    // aliases t2 (25.2MB bf16).
    bf16* t1 = (bf16*)(w + 270848);
    bf16* yv = (bf16*)(w + 270848);
    bf16* xu = (bf16*)(w + 100934144);
    bf16* t2 = (bf16*)(w + 100934144);

    k_init <<<144, 256, 0, stream>>>(W1, b1, W2, b2, coef, W1f, W2A2f, rtab, bias2p);
    k_init2<<<96, 256, 0, stream>>>(atabU, atabL);
    k_up_v <<<1024, 384, 0, stream>>>(x, (const uint4*)atabU, t1);
    k_up_h <<<2048, 384, 0, stream>>>(t1, (const uint4*)atabU, xu);
    k_mlp  <<<512, 1024, 148992, stream>>>(xu, (const uint4*)W1f, (const uint4*)W2A2f,
                                           rtab, bias2p, yv);
    k_lpf_v<<<1024, 384, 0, stream>>>(yv, (const uint4*)atabL, t2);
    k_lpf_h<<<1024, 384, 0, stream>>>(t2, (const uint4*)atabL, out);
}